// Round 1
// 286.931 us; speedup vs baseline: 1.1101x; 1.1101x over previous
//
#include <hip/hip_runtime.h>
#include <stdint.h>

// SparseConv2D as DENSE f16 MFMA GEMM: out[f,hw] = relu(W[f,:] @ X[:,hw] + b[f]).
// R6: abandon the sparse-VALU ELL path (VALU-bound, MfmaUtil=0, ~160us).
// Density is 10% -> dense matrix pipe (34.4 GF @ ~2 PF ~= 17us) beats sparse
// vector pipe (3.44 GF @ ~157 TF + per-nnz LDS reads ~= 80-160us).
//
// Structure: 8 waves/block, block = all 512 filters x 64 hw. X strip staged once
// to LDS as Xt[n][c] f16 (64KiB, 2 blocks/CU), fp32->f16 in-flight. Transpose is
// free via lane->hw staging loads. 16B-slot XOR swizzle (slot ^= n&31) on write
// AND read kills the 1024B-row-stride bank conflicts. K-loop has NO barriers
// (LDS read-only after one syncthreads). A-frags from L2 (W f16 = 512KB,
// L2-resident). mfma_f32_16x16x32_f16, 4x4 tiles/wave, fp32 accum.

#define NF 512
#define NC 512
#define HW 65536
#define BN 64

typedef _Float16 f16x8 __attribute__((ext_vector_type(8)));
typedef _Float16 f16x4 __attribute__((ext_vector_type(4)));
typedef float f32x4 __attribute__((ext_vector_type(4)));

// prep: masked fp32 kernel -> f16 row-major [F][C] in workspace (RNE casts).
__global__ __launch_bounds__(256) void prep_w(const float* __restrict__ kern,
                                              _Float16* __restrict__ wh) {
  const int i = blockIdx.x * 256 + threadIdx.x;  // 65536 threads x 4 elems
  const float4 v = ((const float4*)kern)[i];
  f16x4 o;
  o[0] = (_Float16)v.x;
  o[1] = (_Float16)v.y;
  o[2] = (_Float16)v.z;
  o[3] = (_Float16)v.w;
  ((f16x4*)wh)[i] = o;
}

__global__ __launch_bounds__(512, 4) void spmm_mfma(
    const float* __restrict__ X, const _Float16* __restrict__ Wh,
    const float* __restrict__ bias, float* __restrict__ out) {
  // Xt[n][c], 64 rows x 512 f16 = 64 KiB. 16B slots XOR-swizzled by (n&31).
  __shared__ __align__(16) _Float16 xt[BN * NC];

  const int tid = threadIdx.x;
  const int wave = tid >> 6;   // 0..7
  const int lane = tid & 63;
  const int hw0 = blockIdx.x * BN;

  // ---- stage: lane owns n=lane; wave w owns c in [w*64, w*64+64) ----
  {
    const float* xp = X + hw0 + lane;         // + c*HW per element
    char* rowb = (char*)xt + lane * (NC * 2); // Xt row n=lane
    const int xr = lane & 31;                 // swizzle key
#pragma unroll
    for (int j = 0; j < 8; ++j) {
      const int c0 = wave * 64 + j * 8;
      f16x8 p;
#pragma unroll
      for (int u = 0; u < 8; ++u) p[u] = (_Float16)xp[(size_t)(c0 + u) * HW];
      // slot16 = c0/8, swizzled; b128 write, 8 distinct bank-groups per 8 lanes
      *(f16x8*)(rowb + ((((c0 >> 3) ^ xr)) << 4)) = p;
    }
  }
  __syncthreads();  // only barrier in the kernel

  // ---- compute: wave owns M rows [wave*64, wave*64+64) x all 64 n ----
  const int ln = lane & 15;  // row-in-mtile / col-in-ntile
  const int l4 = lane >> 4;  // k-quarter: k = ks*32 + l4*8 + [0..7]
  const int mrow0 = wave * 64;

  // A: W row-major; lane reads 16B of 8 consecutive k at row mrow0+mt*16+ln
  const _Float16* aptr = Wh + (size_t)(mrow0 + ln) * NC + l4 * 8;

  int bbase[4], bxor[4];
#pragma unroll
  for (int nt = 0; nt < 4; ++nt) {
    const int n = nt * 16 + ln;
    bbase[nt] = n * (NC * 2);
    bxor[nt] = n & 31;
  }

  f32x4 acc[4][4] = {};  // [mt][nt]

#pragma unroll 2
  for (int ks = 0; ks < 16; ++ks) {
    f16x8 a[4], b[4];
#pragma unroll
    for (int mt = 0; mt < 4; ++mt)
      a[mt] = *(const f16x8*)(aptr + (size_t)mt * 16 * NC + ks * 32);
#pragma unroll
    for (int nt = 0; nt < 4; ++nt) {
      const int slot = (ks * 4 + l4) ^ bxor[nt];
      b[nt] = *(const f16x8*)((char*)xt + bbase[nt] + (slot << 4));
    }
#pragma unroll
    for (int nt = 0; nt < 4; ++nt)
#pragma unroll
      for (int mt = 0; mt < 4; ++mt)
        acc[mt][nt] = __builtin_amdgcn_mfma_f32_16x16x32_f16(
            a[mt], b[nt], acc[mt][nt], 0, 0, 0);
  }

  // ---- epilogue: C/D layout col=lane&15 (n), row=(lane>>4)*4+reg (m) ----
#pragma unroll
  for (int mt = 0; mt < 4; ++mt) {
#pragma unroll
    for (int r = 0; r < 4; ++r) {
      const int f = mrow0 + mt * 16 + l4 * 4 + r;
      const float bv = bias[f];
      float* op = out + (size_t)f * HW + hw0 + ln;
#pragma unroll
      for (int nt = 0; nt < 4; ++nt)
        op[nt * 16] = fmaxf(acc[mt][nt][r] + bv, 0.f);
    }
  }
}

extern "C" void kernel_launch(void* const* d_in, const int* in_sizes, int n_in,
                              void* d_out, int out_size, void* d_ws, size_t ws_size,
                              hipStream_t stream) {
  const float* X = (const float*)d_in[0];     // (1, 512, 256, 256) fp32
  const float* kern = (const float*)d_in[1];  // (512, 512) fp32, pre-masked
  // d_in[2] = mask: redundant (kernel already zeroed where mask false)
  const float* bias = (const float*)d_in[3];  // (512,) fp32
  float* out = (float*)d_out;

  _Float16* wh = (_Float16*)d_ws;  // 512 KB f16 W

  prep_w<<<NF * NC / 4 / 256, 256, 0, stream>>>(kern, wh);
  spmm_mfma<<<HW / BN, 512, 0, stream>>>(X, wh, bias, out);
}